// Round 12
// baseline (390.193 us; speedup 1.0000x reference)
//
#include <hip/hip_runtime.h>
#include <cstdint>
#include <cstddef>

// GAT layer, N=8192, Fin=128, Fout=64.
// h = elu( softmax_j(mask(leaky_relu(Wh1_i + Wh2_j))) @ Wh )
// R16 = R14 with ONE lever: SJ 16->32 (JCHUNK 256). Panel 64->32 KB + w2
// 1 KB -> 4 WG/CU -> 4 waves/SIMD: 2x the TLP of every post-R13 variant.
// Tests the last live theory for the ~3 TB/s adj service cap: wave-level
// memory concurrency (R14/R15 showed per-wave depth/burst shape are null).
// Body identical: B-frags + w2 from LDS (lgkmcnt), adj = only vmcnt user,
// depth-2 ping-pong register prefetch. VGPRs trimmed to fit 128/wave.

#define NN   8192
#define FIN  128
#define FOUT 64
#define SJ   32                // j-split per 32-row group: 256*SJ = 8192 tasks
#define JCHUNK (NN / SJ)       // 256 columns per wave -> 8 blocks of 32

typedef __attribute__((ext_vector_type(8))) short   short8;   // 8 bf16 (4 VGPRs)
typedef __attribute__((ext_vector_type(4))) float   f32x4;

#define LOG2E 1.44269504088896340736f
#define NTL(p) __builtin_nontemporal_load((const f32x4*)(p))

// ---------------------------------------------------------------- Phase A ---
// One wave per 4 rows: Wh[row][f] (f = lane). Emits:
//  - WhP packed B-fragments: WhP[(B0*4+ft)*512 + lane*8 + e] =
//      bf16(Wh[B0*32 + (lane>>4)*8 + e][ (ft*16) + (lane&15) ])
//    i.e. exactly the 16B lane (m,q) consumes as MFMA-B in phaseB.
//  - Wh1/Wh2 = Wh.a1 / Wh.a2, pre-scaled by log2e (exp2 domain; leaky_relu
//    commutes with positive scaling).
__global__ __launch_bounds__(256) void gat_phaseA(
    const float* __restrict__ x, const float* __restrict__ W,
    const float* __restrict__ a, unsigned short* __restrict__ WhP,
    float* __restrict__ Wh1, float* __restrict__ Wh2)
{
  const int wid  = threadIdx.x >> 6;
  const int lane = threadIdx.x & 63;
  const int row0 = (blockIdx.x * 4 + wid) * 4;
  const float a1 = a[lane];
  const float a2 = a[FOUT + lane];
  float acc[4] = {0.f, 0.f, 0.f, 0.f};
#pragma unroll 4
  for (int k = 0; k < FIN; k += 4) {
    float4 wv0 = make_float4(W[(k+0)*FOUT + lane], W[(k+1)*FOUT + lane],
                             W[(k+2)*FOUT + lane], W[(k+3)*FOUT + lane]);
#pragma unroll
    for (int r = 0; r < 4; ++r) {
      float4 xv = *(const float4*)(x + (row0 + r) * FIN + k);
      acc[r] = fmaf(xv.x, wv0.x, acc[r]);
      acc[r] = fmaf(xv.y, wv0.y, acc[r]);
      acc[r] = fmaf(xv.z, wv0.z, acc[r]);
      acc[r] = fmaf(xv.w, wv0.w, acc[r]);
    }
  }
  const int ft = lane >> 4, m = lane & 15;
#pragma unroll
  for (int r = 0; r < 4; ++r) {
    const int row = row0 + r;
    // bf16 round-to-nearest-even
    unsigned int u = __float_as_uint(acc[r]);
    unsigned int rb = (u + 0x7FFFu + ((u >> 16) & 1u)) >> 16;
    // packed-fragment dest: B0=row>>5, q=(row>>3)&3, e=row&7
    const int B0 = row >> 5, qq = (row >> 3) & 3, e = row & 7;
    WhP[(size_t)(B0 * 4 + ft) * 512 + (qq * 16 + m) * 8 + e] = (unsigned short)rb;
    float s1 = acc[r] * a1, s2 = acc[r] * a2;
#pragma unroll
    for (int off = 32; off; off >>= 1) {
      s1 += __shfl_xor(s1, off);
      s2 += __shfl_xor(s2, off);
    }
    if (lane == 0) { Wh1[row] = s1 * LOG2E; Wh2[row] = s2 * LOG2E; }
  }
}

// ---------------------------------------------------------------- Phase B ---
// Wave task = (rowGroup of 32 rows) x (j-chunk of 256). 4 waves/WG share the
// j-chunk; packed-B panel (32 KB) + Wh2 chunk (1 KB) staged in LDS once.
// Body: 4 ds_read_b128 B-frags + 2 ds_read w2 (lgkmcnt, hidden under af
// compute); adj is the ONLY vmcnt user, depth-2 ping-pong register prefetch.
// 8 blocks of 32 cols, unrolled x2.
#define AF_ONE(AF, AD0, AD1, W20, W21, WH1, RS)                          \
    _Pragma("unroll")                                                    \
    for (int e = 0; e < 4; ++e) {                                        \
      float t0 = (WH1) + (W20)[e];                                       \
      t0 = fmaxf(t0, 0.2f * t0);            /* leaky_relu, scale-inv */  \
      float p0 = exp2f(t0) * (AD0)[e];      /* mask: adj is 0.0/1.0 */   \
      unsigned int pu0 = __float_as_uint(p0) & 0xFFFF0000u;              \
      RS += __uint_as_float(pu0);           /* denom matches bf16 num */ \
      AF[e] = (short)(pu0 >> 16);                                        \
      float t1 = (WH1) + (W21)[e];                                       \
      t1 = fmaxf(t1, 0.2f * t1);                                         \
      float p1 = exp2f(t1) * (AD1)[e];                                   \
      unsigned int pu1 = __float_as_uint(p1) & 0xFFFF0000u;              \
      RS += __uint_as_float(pu1);                                        \
      AF[4 + e] = (short)(pu1 >> 16);                                    \
    }

#define GAT_BODY(AD00, AD01, AD10, AD11, BLK, JPF)                       \
  {                                                                      \
    const unsigned short* pb = panel + (BLK) * 2048 + lane * 8;          \
    short8 b0 = *(const short8*)(pb);                                    \
    short8 b1 = *(const short8*)(pb + 512);                              \
    short8 b2 = *(const short8*)(pb + 1024);                             \
    short8 b3 = *(const short8*)(pb + 1536);                             \
    const float* wp = w2lds + (BLK) * 32 + q * 8;                        \
    f32x4 w20 = *(const f32x4*)(wp);                                     \
    f32x4 w21 = *(const f32x4*)(wp + 4);                                 \
    short8 af0, af1;                                                     \
    AF_ONE(af0, AD00, AD01, w20, w21, wh1_0, rsum0);                     \
    AF_ONE(af1, AD10, AD11, w20, w21, wh1_1, rsum1);                     \
    AD00 = NTL(adjrow0 + (JPF)); AD01 = NTL(adjrow0 + (JPF) + 4);        \
    AD10 = NTL(adjrow1 + (JPF)); AD11 = NTL(adjrow1 + (JPF) + 4);        \
    c00 = __builtin_amdgcn_mfma_f32_16x16x32_bf16(af0, b0, c00, 0,0,0);  \
    c01 = __builtin_amdgcn_mfma_f32_16x16x32_bf16(af0, b1, c01, 0,0,0);  \
    c02 = __builtin_amdgcn_mfma_f32_16x16x32_bf16(af0, b2, c02, 0,0,0);  \
    c03 = __builtin_amdgcn_mfma_f32_16x16x32_bf16(af0, b3, c03, 0,0,0);  \
    c10 = __builtin_amdgcn_mfma_f32_16x16x32_bf16(af1, b0, c10, 0,0,0);  \
    c11 = __builtin_amdgcn_mfma_f32_16x16x32_bf16(af1, b1, c11, 0,0,0);  \
    c12 = __builtin_amdgcn_mfma_f32_16x16x32_bf16(af1, b2, c12, 0,0,0);  \
    c13 = __builtin_amdgcn_mfma_f32_16x16x32_bf16(af1, b3, c13, 0,0,0);  \
  }

__global__ __launch_bounds__(256, 4) void gat_phaseB(
    const float* __restrict__ adj, const unsigned short* __restrict__ WhP,
    const float* __restrict__ Wh1, const float* __restrict__ Wh2,
    float* __restrict__ accbuf, float* __restrict__ denbuf, int nslices)
{
  const int wid  = threadIdx.x >> 6;
  const int lane = threadIdx.x & 63;
  // 4 waves of a WG share the j-chunk, cover 4 row-groups
  const int jc   = blockIdx.x % SJ;
  const int rg   = (blockIdx.x / SJ) * 4 + wid;   // 32-row group
  const int m = lane & 15;
  const int q = lane >> 4;
  const int r0 = rg * 32 + m;
  const int r1 = r0 + 16;
  const float wh1_0 = Wh1[r0];
  const float wh1_1 = Wh1[r1];
  // per-lane bases with the q*8 element offset folded in
  const float* adjrow0 = adj + (size_t)r0 * NN + q * 8;
  const float* adjrow1 = adj + (size_t)r1 * NN + q * 8;

  const int jbeg = jc * JCHUNK;

  // depth-2 ping-pong adj slots
  f32x4 adA00, adA01, adA10, adA11;    // even blocks
  f32x4 adB00, adB01, adB10, adB11;    // odd blocks
  adA00 = NTL(adjrow0 + jbeg);      adA01 = NTL(adjrow0 + jbeg + 4);
  adA10 = NTL(adjrow1 + jbeg);      adA11 = NTL(adjrow1 + jbeg + 4);
  adB00 = NTL(adjrow0 + jbeg + 32); adB01 = NTL(adjrow0 + jbeg + 36);
  adB10 = NTL(adjrow1 + jbeg + 32); adB11 = NTL(adjrow1 + jbeg + 36);

  // ---- LDS: 32 KB packed-B panel + 1 KB Wh2 chunk for this jc
  __shared__ __align__(16) unsigned short panel[8 * 2048];
  __shared__ __align__(16) float w2lds[JCHUNK];
  {
    const f32x4* src = (const f32x4*)(WhP + (size_t)jc * 8 * 2048) + threadIdx.x;
    f32x4* dst = (f32x4*)panel + threadIdx.x;
#pragma unroll
    for (int k = 0; k < 8; ++k)
      dst[k * 256] = src[k * 256];     // 256 thr x 16B = 4 KB per step
    if (threadIdx.x < JCHUNK / 4)
      ((f32x4*)w2lds)[threadIdx.x] =
          ((const f32x4*)(Wh2 + jbeg))[threadIdx.x];
  }
  __syncthreads();

  f32x4 c00 = {0.f,0.f,0.f,0.f}, c01 = c00, c02 = c00, c03 = c00;
  f32x4 c10 = c00, c11 = c00, c12 = c00, c13 = c00;
  float rsum0 = 0.f, rsum1 = 0.f;

  // 8 blocks of 32 columns; unrolled x2 -> 4 static double-bodies. Tail
  // prefetches wrap (valid addresses, values unused).
#pragma unroll
  for (int bb = 0; bb < 8; bb += 2) {
    GAT_BODY(adA00, adA01, adA10, adA11, bb,     jbeg + ((bb + 2) & 7) * 32);
    GAT_BODY(adB00, adB01, adB10, adB11, bb + 1, jbeg + ((bb + 3) & 7) * 32);
  }

  // row-sums: combine the 4 k-quads; every lane ends with full sum for its m
  rsum0 += __shfl_xor(rsum0, 16);
  rsum0 += __shfl_xor(rsum0, 32);
  rsum1 += __shfl_xor(rsum1, 16);
  rsum1 += __shfl_xor(rsum1, 32);

  const int slice = (nslices > 1) ? jc : 0;
  float* accout = accbuf + (size_t)slice * (NN * FOUT);
  float* denout = denbuf + slice * NN;
  f32x4 cc0[4] = {c00, c01, c02, c03};
  f32x4 cc1[4] = {c10, c11, c12, c13};
  if (nslices > 1) {            // roomy ws: plain per-slice stores
    if (q == 0) { denout[r0] = rsum0; denout[r1] = rsum1; }
#pragma unroll
    for (int ft = 0; ft < 4; ++ft)
#pragma unroll
      for (int r = 0; r < 4; ++r) {
        accout[(rg * 32 +      q * 4 + r) * FOUT + ft * 16 + m] = cc0[ft][r];
        accout[(rg * 32 + 16 + q * 4 + r) * FOUT + ft * 16 + m] = cc1[ft][r];
      }
  } else {                      // tight ws: atomic accumulate (zeroed first)
    if (q == 0) { atomicAdd(&denout[r0], rsum0); atomicAdd(&denout[r1], rsum1); }
#pragma unroll
    for (int ft = 0; ft < 4; ++ft)
#pragma unroll
      for (int r = 0; r < 4; ++r) {
        atomicAdd(&accout[(rg * 32 +      q * 4 + r) * FOUT + ft * 16 + m], cc0[ft][r]);
        atomicAdd(&accout[(rg * 32 + 16 + q * 4 + r) * FOUT + ft * 16 + m], cc1[ft][r]);
      }
  }
}

// ---------------------------------------------------------------- Phase C ---
// elu(acc/den), vectorized f32x4 per thread.
__global__ __launch_bounds__(256) void gat_phaseC(
    const float* __restrict__ accbuf, const float* __restrict__ denbuf,
    float* __restrict__ out, int nslices)
{
  const int idx4 = blockIdx.x * 256 + threadIdx.x;   // f32x4 index
  const int idx  = idx4 * 4;
  const int row  = idx >> 6;    // FOUT = 64; 4 elems stay within one row
  f32x4 s = {0.f, 0.f, 0.f, 0.f};
  float d = 0.f;
  for (int sl = 0; sl < nslices; ++sl) {
    f32x4 v = *(const f32x4*)(accbuf + (size_t)sl * (NN * FOUT) + idx);
    s += v;
    d += denbuf[sl * NN + row];
  }
  float inv = 1.0f / d;
  f32x4 o;
#pragma unroll
  for (int e = 0; e < 4; ++e) {
    float v = s[e] * inv;
    o[e] = (v > 0.f) ? v : expm1f(v);   // elu, alpha=1
  }
  *(f32x4*)(out + idx) = o;
}

// ------------------------------------------------------------------ launch --
extern "C" void kernel_launch(void* const* d_in, const int* in_sizes, int n_in,
                              void* d_out, int out_size, void* d_ws, size_t ws_size,
                              hipStream_t stream)
{
  const float* x   = (const float*)d_in[0];   // [8192,128]
  const float* adj = (const float*)d_in[1];   // [8192,8192]
  const float* W   = (const float*)d_in[2];   // [128,64]
  const float* a   = (const float*)d_in[3];   // [128,1]
  float* out = (float*)d_out;                 // [8192,64] fp32

  const size_t accEl = (size_t)NN * FOUT;
  const size_t whpBytes = (size_t)(NN / 32) * 4 * 512 * 2;   // 1 MB packed B
  const size_t roomyBytes = (size_t)SJ * accEl * 4 + (size_t)SJ * NN * 4
                          + (size_t)NN * 8 + whpBytes;
  const int nslices = (ws_size >= roomyBytes) ? SJ : 1;

  char* ws = (char*)d_ws;
  float* accbuf = (float*)ws;
  size_t off = (size_t)nslices * accEl * 4;
  float* denbuf = (float*)(ws + off); off += (size_t)nslices * NN * 4;
  float* Wh1 = (float*)(ws + off);    off += (size_t)NN * 4;
  float* Wh2 = (float*)(ws + off);    off += (size_t)NN * 4;
  unsigned short* WhP = (unsigned short*)(ws + off);

  if (nslices == 1)   // atomic path needs zeroed acc+den (contiguous)
    hipMemsetAsync(accbuf, 0, accEl * 4 + (size_t)NN * 4, stream);

  gat_phaseA<<<NN / 16, 256, 0, stream>>>(x, W, a, WhP, Wh1, Wh2);
  gat_phaseB<<<((NN / 32) * SJ) / 4, 256, 0, stream>>>(adj, WhP, Wh1, Wh2,
                                                       accbuf, denbuf, nslices);
  gat_phaseC<<<(NN * FOUT) / 4 / 256, 256, 0, stream>>>(accbuf, denbuf, out, nslices);
}

// Round 13
// 378.044 us; speedup vs baseline: 1.0321x; 1.0321x over previous
//
#include <hip/hip_runtime.h>
#include <cstdint>
#include <cstddef>

// GAT layer, N=8192, Fin=128, Fout=64.
// h = elu( softmax_j(mask(leaky_relu(Wh1_i + Wh2_j))) @ Wh )
// R17 = R14 (champion, 377us) + SEPARABLE-EXP: exp2(max(z,.2z)) =
// max(exp2 z, exp2 .2z) (exp2 monotone), and each branch factors per
// row/col: u_i v_j and p_i q_j. phaseA emits u,p per row and v,q per col;
// phaseB's af chain loses its 16 transcendentals/body and the adj-dependent
// tail shrinks to mul+pack. Discovery driving this: R8 counters show the
// harness's 1-GiB ws-poison fill (6.7 TB/s) OVERLAPS phaseB (1.5 TB/s) --
// sum = HBM peak. phaseB is bandwidth-starved; only raw time cuts show
// through. Structure (LDS B-panel, w2 in LDS, distance-4 adj slots) = R14.

#define NN   8192
#define FIN  128
#define FOUT 64
#define SJ   16                // j-split per 32-row group: 256*SJ = 4096 tasks
#define JCHUNK (NN / SJ)       // 512 columns per wave -> 16 blocks of 32

typedef __attribute__((ext_vector_type(8))) short   short8;   // 8 bf16 (4 VGPRs)
typedef __attribute__((ext_vector_type(4))) float   f32x4;

#define LOG2E 1.44269504088896340736f
#define NTL(p) __builtin_nontemporal_load((const f32x4*)(p))

// ---------------------------------------------------------------- Phase A ---
// One wave per 4 rows: Wh[row][f] (f = lane). Emits:
//  - WhP packed B-fragments (exactly the 16B lane (m,q) consumes in phaseB).
//  - u=exp2(s1*L), p=exp2(.2*s1*L) per row; v=exp2(s2*L), q=exp2(.2*s2*L)
//    per col (s1=Wh.a1, s2=Wh.a2). Separable-exp operands for phaseB.
__global__ __launch_bounds__(256) void gat_phaseA(
    const float* __restrict__ x, const float* __restrict__ W,
    const float* __restrict__ a, unsigned short* __restrict__ WhP,
    float* __restrict__ Wh1u, float* __restrict__ Wh1p,
    float* __restrict__ Wh2v, float* __restrict__ Wh2q)
{
  const int wid  = threadIdx.x >> 6;
  const int lane = threadIdx.x & 63;
  const int row0 = (blockIdx.x * 4 + wid) * 4;
  const float a1 = a[lane];
  const float a2 = a[FOUT + lane];
  float acc[4] = {0.f, 0.f, 0.f, 0.f};
#pragma unroll 4
  for (int k = 0; k < FIN; k += 4) {
    float4 wv0 = make_float4(W[(k+0)*FOUT + lane], W[(k+1)*FOUT + lane],
                             W[(k+2)*FOUT + lane], W[(k+3)*FOUT + lane]);
#pragma unroll
    for (int r = 0; r < 4; ++r) {
      float4 xv = *(const float4*)(x + (row0 + r) * FIN + k);
      acc[r] = fmaf(xv.x, wv0.x, acc[r]);
      acc[r] = fmaf(xv.y, wv0.y, acc[r]);
      acc[r] = fmaf(xv.z, wv0.z, acc[r]);
      acc[r] = fmaf(xv.w, wv0.w, acc[r]);
    }
  }
  const int ft = lane >> 4, m = lane & 15;
#pragma unroll
  for (int r = 0; r < 4; ++r) {
    const int row = row0 + r;
    // bf16 round-to-nearest-even
    unsigned int u = __float_as_uint(acc[r]);
    unsigned int rb = (u + 0x7FFFu + ((u >> 16) & 1u)) >> 16;
    // packed-fragment dest: B0=row>>5, q=(row>>3)&3, e=row&7
    const int B0 = row >> 5, qq = (row >> 3) & 3, e = row & 7;
    WhP[(size_t)(B0 * 4 + ft) * 512 + (qq * 16 + m) * 8 + e] = (unsigned short)rb;
    float s1 = acc[r] * a1, s2 = acc[r] * a2;
#pragma unroll
    for (int off = 32; off; off >>= 1) {
      s1 += __shfl_xor(s1, off);
      s2 += __shfl_xor(s2, off);
    }
    if (lane == 0) {
      float z1 = s1 * LOG2E, z2 = s2 * LOG2E;
      Wh1u[row] = exp2f(z1); Wh1p[row] = exp2f(0.2f * z1);
      Wh2v[row] = exp2f(z2); Wh2q[row] = exp2f(0.2f * z2);
    }
  }
}

// ---------------------------------------------------------------- Phase B ---
// Wave task = (rowGroup of 32 rows) x (j-chunk of 512). 4 waves/WG share the
// j-chunk; packed-B panel (64 KB) + v,q chunks (4 KB) staged in LDS once.
// Body: B-frags + v,q from LDS (lgkmcnt); adj = only vmcnt user, distance-4
// register slots. Numerator: num = adj * max(u*v, p*q) -- no transcendental,
// adj-dependent tail = 1 mul + pack.
#define AF_ONE(AF, AD0, AD1, WV0, WV1, WQ0, WQ1, UU, PP, RS)             \
    _Pragma("unroll")                                                    \
    for (int e = 0; e < 4; ++e) {                                        \
      float m0 = fmaxf((UU) * (WV0)[e], (PP) * (WQ0)[e]);                \
      float n0 = m0 * (AD0)[e];             /* mask: adj is 0.0/1.0 */   \
      unsigned int pu0 = __float_as_uint(n0) & 0xFFFF0000u;              \
      RS += __uint_as_float(pu0);           /* denom matches bf16 num */ \
      AF[e] = (short)(pu0 >> 16);                                        \
      float m1 = fmaxf((UU) * (WV1)[e], (PP) * (WQ1)[e]);                \
      float n1 = m1 * (AD1)[e];                                          \
      unsigned int pu1 = __float_as_uint(n1) & 0xFFFF0000u;              \
      RS += __uint_as_float(pu1);                                        \
      AF[4 + e] = (short)(pu1 >> 16);                                    \
    }

#define GAT_BODY(AD00, AD01, AD10, AD11, BLK, JPF)                       \
  {                                                                      \
    const unsigned short* pb = panel + (BLK) * 2048 + lane * 8;          \
    short8 b0 = *(const short8*)(pb);                                    \
    short8 b1 = *(const short8*)(pb + 512);                              \
    short8 b2 = *(const short8*)(pb + 1024);                             \
    short8 b3 = *(const short8*)(pb + 1536);                             \
    const int wo = (BLK) * 32 + q * 8;                                   \
    f32x4 wv0 = *(const f32x4*)(w2v + wo);                               \
    f32x4 wv1 = *(const f32x4*)(w2v + wo + 4);                           \
    f32x4 wq0 = *(const f32x4*)(w2q + wo);                               \
    f32x4 wq1 = *(const f32x4*)(w2q + wo + 4);                           \
    short8 af0, af1;                                                     \
    AF_ONE(af0, AD00, AD01, wv0, wv1, wq0, wq1, u_0, p_0, rsum0);        \
    AF_ONE(af1, AD10, AD11, wv0, wv1, wq0, wq1, u_1, p_1, rsum1);        \
    AD00 = NTL(adjrow0 + (JPF)); AD01 = NTL(adjrow0 + (JPF) + 4);        \
    AD10 = NTL(adjrow1 + (JPF)); AD11 = NTL(adjrow1 + (JPF) + 4);        \
    c00 = __builtin_amdgcn_mfma_f32_16x16x32_bf16(af0, b0, c00, 0,0,0);  \
    c01 = __builtin_amdgcn_mfma_f32_16x16x32_bf16(af0, b1, c01, 0,0,0);  \
    c02 = __builtin_amdgcn_mfma_f32_16x16x32_bf16(af0, b2, c02, 0,0,0);  \
    c03 = __builtin_amdgcn_mfma_f32_16x16x32_bf16(af0, b3, c03, 0,0,0);  \
    c10 = __builtin_amdgcn_mfma_f32_16x16x32_bf16(af1, b0, c10, 0,0,0);  \
    c11 = __builtin_amdgcn_mfma_f32_16x16x32_bf16(af1, b1, c11, 0,0,0);  \
    c12 = __builtin_amdgcn_mfma_f32_16x16x32_bf16(af1, b2, c12, 0,0,0);  \
    c13 = __builtin_amdgcn_mfma_f32_16x16x32_bf16(af1, b3, c13, 0,0,0);  \
  }

__global__ __launch_bounds__(256, 2) void gat_phaseB(
    const float* __restrict__ adj, const unsigned short* __restrict__ WhP,
    const float* __restrict__ Wh1u, const float* __restrict__ Wh1p,
    const float* __restrict__ Wh2v, const float* __restrict__ Wh2q,
    float* __restrict__ accbuf, float* __restrict__ denbuf, int nslices)
{
  const int wid  = threadIdx.x >> 6;
  const int lane = threadIdx.x & 63;
  // 4 waves of a WG share the j-chunk, cover 4 row-groups
  const int jc   = blockIdx.x % SJ;
  const int rg   = (blockIdx.x / SJ) * 4 + wid;   // 32-row group
  const int m = lane & 15;
  const int q = lane >> 4;
  const int r0 = rg * 32 + m;
  const int r1 = r0 + 16;
  const float u_0 = Wh1u[r0], p_0 = Wh1p[r0];
  const float u_1 = Wh1u[r1], p_1 = Wh1p[r1];
  // per-lane bases with the q*8 element offset folded in
  const float* adjrow0 = adj + (size_t)r0 * NN + q * 8;
  const float* adjrow1 = adj + (size_t)r1 * NN + q * 8;

  const int jbeg = jc * JCHUNK;

  // ---- adj prologue: distance-4 slots (issued first, deepest in queue)
  f32x4 aS00, aS01, aS10, aS11;   // slot A: block 0
  f32x4 bS00, bS01, bS10, bS11;   // slot B: block 1
  f32x4 cS00, cS01, cS10, cS11;   // slot C: block 2
  f32x4 dS00, dS01, dS10, dS11;   // slot D: block 3
  aS00 = NTL(adjrow0 + jbeg);       aS01 = NTL(adjrow0 + jbeg + 4);
  aS10 = NTL(adjrow1 + jbeg);       aS11 = NTL(adjrow1 + jbeg + 4);
  bS00 = NTL(adjrow0 + jbeg + 32);  bS01 = NTL(adjrow0 + jbeg + 36);
  bS10 = NTL(adjrow1 + jbeg + 32);  bS11 = NTL(adjrow1 + jbeg + 36);
  cS00 = NTL(adjrow0 + jbeg + 64);  cS01 = NTL(adjrow0 + jbeg + 68);
  cS10 = NTL(adjrow1 + jbeg + 64);  cS11 = NTL(adjrow1 + jbeg + 68);
  dS00 = NTL(adjrow0 + jbeg + 96);  dS01 = NTL(adjrow0 + jbeg + 100);
  dS10 = NTL(adjrow1 + jbeg + 96);  dS11 = NTL(adjrow1 + jbeg + 100);

  // ---- LDS: 64 KB packed-B panel + 2x2 KB v,q chunks for this jc
  __shared__ __align__(16) unsigned short panel[16 * 2048];
  __shared__ __align__(16) float w2v[JCHUNK];
  __shared__ __align__(16) float w2q[JCHUNK];
  {
    const f32x4* src = (const f32x4*)(WhP + (size_t)jc * 16 * 2048) + threadIdx.x;
    f32x4* dst = (f32x4*)panel + threadIdx.x;
#pragma unroll
    for (int k = 0; k < 16; ++k)
      dst[k * 256] = src[k * 256];     // 256 thr x 16B = 4 KB per step
    if (threadIdx.x < 128)
      ((f32x4*)w2v)[threadIdx.x] = ((const f32x4*)(Wh2v + jbeg))[threadIdx.x];
    else
      ((f32x4*)w2q)[threadIdx.x - 128] =
          ((const f32x4*)(Wh2q + jbeg))[threadIdx.x - 128];
  }
  __syncthreads();

  f32x4 c00 = {0.f,0.f,0.f,0.f}, c01 = c00, c02 = c00, c03 = c00;
  f32x4 c10 = c00, c11 = c00, c12 = c00, c13 = c00;
  float rsum0 = 0.f, rsum1 = 0.f;

  // 16 blocks of 32 columns; 4-slot rotation, distance-4 prefetch. Tail
  // prefetches wrap (valid addresses, values unused).
#pragma unroll
  for (int bb = 0; bb < 16; bb += 4) {
    GAT_BODY(aS00, aS01, aS10, aS11, bb,     jbeg + ((bb + 4) & 15) * 32);
    GAT_BODY(bS00, bS01, bS10, bS11, bb + 1, jbeg + ((bb + 5) & 15) * 32);
    GAT_BODY(cS00, cS01, cS10, cS11, bb + 2, jbeg + ((bb + 6) & 15) * 32);
    GAT_BODY(dS00, dS01, dS10, dS11, bb + 3, jbeg + ((bb + 7) & 15) * 32);
  }

  // row-sums: combine the 4 k-quads; every lane ends with full sum for its m
  rsum0 += __shfl_xor(rsum0, 16);
  rsum0 += __shfl_xor(rsum0, 32);
  rsum1 += __shfl_xor(rsum1, 16);
  rsum1 += __shfl_xor(rsum1, 32);

  const int slice = (nslices > 1) ? jc : 0;
  float* accout = accbuf + (size_t)slice * (NN * FOUT);
  float* denout = denbuf + slice * NN;
  f32x4 cc0[4] = {c00, c01, c02, c03};
  f32x4 cc1[4] = {c10, c11, c12, c13};
  if (nslices > 1) {            // roomy ws: plain per-slice stores
    if (q == 0) { denout[r0] = rsum0; denout[r1] = rsum1; }
#pragma unroll
    for (int ft = 0; ft < 4; ++ft)
#pragma unroll
      for (int r = 0; r < 4; ++r) {
        accout[(rg * 32 +      q * 4 + r) * FOUT + ft * 16 + m] = cc0[ft][r];
        accout[(rg * 32 + 16 + q * 4 + r) * FOUT + ft * 16 + m] = cc1[ft][r];
      }
  } else {                      // tight ws: atomic accumulate (zeroed first)
    if (q == 0) { atomicAdd(&denout[r0], rsum0); atomicAdd(&denout[r1], rsum1); }
#pragma unroll
    for (int ft = 0; ft < 4; ++ft)
#pragma unroll
      for (int r = 0; r < 4; ++r) {
        atomicAdd(&accout[(rg * 32 +      q * 4 + r) * FOUT + ft * 16 + m], cc0[ft][r]);
        atomicAdd(&accout[(rg * 32 + 16 + q * 4 + r) * FOUT + ft * 16 + m], cc1[ft][r]);
      }
  }
}

// ---------------------------------------------------------------- Phase C ---
// elu(acc/den), vectorized f32x4 per thread.
__global__ __launch_bounds__(256) void gat_phaseC(
    const float* __restrict__ accbuf, const float* __restrict__ denbuf,
    float* __restrict__ out, int nslices)
{
  const int idx4 = blockIdx.x * 256 + threadIdx.x;   // f32x4 index
  const int idx  = idx4 * 4;
  const int row  = idx >> 6;    // FOUT = 64; 4 elems stay within one row
  f32x4 s = {0.f, 0.f, 0.f, 0.f};
  float d = 0.f;
  for (int sl = 0; sl < nslices; ++sl) {
    f32x4 v = *(const f32x4*)(accbuf + (size_t)sl * (NN * FOUT) + idx);
    s += v;
    d += denbuf[sl * NN + row];
  }
  float inv = 1.0f / d;
  f32x4 o;
#pragma unroll
  for (int e = 0; e < 4; ++e) {
    float v = s[e] * inv;
    o[e] = (v > 0.f) ? v : expm1f(v);   // elu, alpha=1
  }
  *(f32x4*)(out + idx) = o;
}

// ------------------------------------------------------------------ launch --
extern "C" void kernel_launch(void* const* d_in, const int* in_sizes, int n_in,
                              void* d_out, int out_size, void* d_ws, size_t ws_size,
                              hipStream_t stream)
{
  const float* x   = (const float*)d_in[0];   // [8192,128]
  const float* adj = (const float*)d_in[1];   // [8192,8192]
  const float* W   = (const float*)d_in[2];   // [128,64]
  const float* a   = (const float*)d_in[3];   // [128,1]
  float* out = (float*)d_out;                 // [8192,64] fp32

  const size_t accEl = (size_t)NN * FOUT;
  const size_t whpBytes = (size_t)(NN / 32) * 4 * 512 * 2;   // 1 MB packed B
  const size_t roomyBytes = (size_t)SJ * accEl * 4 + (size_t)SJ * NN * 4
                          + (size_t)NN * 16 + whpBytes;
  const int nslices = (ws_size >= roomyBytes) ? SJ : 1;

  char* ws = (char*)d_ws;
  float* accbuf = (float*)ws;
  size_t off = (size_t)nslices * accEl * 4;
  float* denbuf = (float*)(ws + off); off += (size_t)nslices * NN * 4;
  float* Wh1u = (float*)(ws + off);   off += (size_t)NN * 4;
  float* Wh1p = (float*)(ws + off);   off += (size_t)NN * 4;
  float* Wh2v = (float*)(ws + off);   off += (size_t)NN * 4;
  float* Wh2q = (float*)(ws + off);   off += (size_t)NN * 4;
  unsigned short* WhP = (unsigned short*)(ws + off);

  if (nslices == 1)   // atomic path needs zeroed acc+den (contiguous)
    hipMemsetAsync(accbuf, 0, accEl * 4 + (size_t)NN * 4, stream);

  gat_phaseA<<<NN / 16, 256, 0, stream>>>(x, W, a, WhP, Wh1u, Wh1p, Wh2v, Wh2q);
  gat_phaseB<<<((NN / 32) * SJ) / 4, 256, 0, stream>>>(adj, WhP, Wh1u, Wh1p,
                                                       Wh2v, Wh2q,
                                                       accbuf, denbuf, nslices);
  gat_phaseC<<<(NN * FOUT) / 4 / 256, 256, 0, stream>>>(accbuf, denbuf, out, nslices);
}

// Round 14
// 373.432 us; speedup vs baseline: 1.0449x; 1.0123x over previous
//
#include <hip/hip_runtime.h>
#include <cstdint>
#include <cstddef>

// GAT layer, N=8192, Fin=128, Fout=64.
// h = elu( softmax_j(mask(leaky_relu(Wh1_i + Wh2_j))) @ Wh )
// R18 = R14 (champion 377us) with the twice-validated lever (R9 -34us,
// R13 -16us: fewer vmcnt wait-points per unit work) pushed to the register
// limit: 64 rows/wave (4 sub-tiles sharing every B-frag, w2 read, and the
// single per-body adj slot-rotation wait). ~190 VGPR at launch_bounds(256,2)
// budget 256. 2048 tasks = exact 1-round residency (2 WG/CU x 4 waves x
// 256 CU) -- no second-round prologues. Body: B+w2 from LDS (lgkmcnt);
// adj = only vmcnt user, depth-2 ping-pong x 4 subtiles (16 KB/wave in
// flight); 16 MFMA/body.

#define NN   8192
#define FIN  128
#define FOUT 64
#define SJ   16                // j-split; tasks = (NN/64)*SJ = 2048 waves
#define JCHUNK (NN / SJ)       // 512 columns per wave -> 16 blocks of 32

typedef __attribute__((ext_vector_type(8))) short   short8;   // 8 bf16 (4 VGPRs)
typedef __attribute__((ext_vector_type(4))) float   f32x4;

#define LOG2E 1.44269504088896340736f
#define NTL(p) __builtin_nontemporal_load((const f32x4*)(p))

// ---------------------------------------------------------------- Phase A ---
// One wave per 4 rows: Wh[row][f] (f = lane). Emits:
//  - WhP packed B-fragments: WhP[(B0*4+ft)*512 + (qq*16+m)*8 + e] =
//      bf16(Wh[B0*32 + qq*8 + e][ft*16 + m]) -- exactly the 16B lane (m,q)
//      consumes as MFMA-B in phaseB.
//  - Wh1/Wh2 = Wh.a1 / Wh.a2, pre-scaled by log2e (exp2 domain; leaky_relu
//    commutes with positive scaling).
__global__ __launch_bounds__(256) void gat_phaseA(
    const float* __restrict__ x, const float* __restrict__ W,
    const float* __restrict__ a, unsigned short* __restrict__ WhP,
    float* __restrict__ Wh1, float* __restrict__ Wh2)
{
  const int wid  = threadIdx.x >> 6;
  const int lane = threadIdx.x & 63;
  const int row0 = (blockIdx.x * 4 + wid) * 4;
  const float a1 = a[lane];
  const float a2 = a[FOUT + lane];
  float acc[4] = {0.f, 0.f, 0.f, 0.f};
#pragma unroll 4
  for (int k = 0; k < FIN; k += 4) {
    float4 wv0 = make_float4(W[(k+0)*FOUT + lane], W[(k+1)*FOUT + lane],
                             W[(k+2)*FOUT + lane], W[(k+3)*FOUT + lane]);
#pragma unroll
    for (int r = 0; r < 4; ++r) {
      float4 xv = *(const float4*)(x + (row0 + r) * FIN + k);
      acc[r] = fmaf(xv.x, wv0.x, acc[r]);
      acc[r] = fmaf(xv.y, wv0.y, acc[r]);
      acc[r] = fmaf(xv.z, wv0.z, acc[r]);
      acc[r] = fmaf(xv.w, wv0.w, acc[r]);
    }
  }
  const int ft = lane >> 4, m = lane & 15;
#pragma unroll
  for (int r = 0; r < 4; ++r) {
    const int row = row0 + r;
    // bf16 round-to-nearest-even
    unsigned int u = __float_as_uint(acc[r]);
    unsigned int rb = (u + 0x7FFFu + ((u >> 16) & 1u)) >> 16;
    // packed-fragment dest: B0=row>>5, q=(row>>3)&3, e=row&7
    const int B0 = row >> 5, qq = (row >> 3) & 3, e = row & 7;
    WhP[(size_t)(B0 * 4 + ft) * 512 + (qq * 16 + m) * 8 + e] = (unsigned short)rb;
    float s1 = acc[r] * a1, s2 = acc[r] * a2;
#pragma unroll
    for (int off = 32; off; off >>= 1) {
      s1 += __shfl_xor(s1, off);
      s2 += __shfl_xor(s2, off);
    }
    if (lane == 0) { Wh1[row] = s1 * LOG2E; Wh2[row] = s2 * LOG2E; }
  }
}

// ---------------------------------------------------------------- Phase B ---
// Wave task = (rowGroup of 64 rows) x (j-chunk of 512). 4 sub-tiles per wave
// (rows m, m+16, m+32, m+48) share every B-frag/w2 read and the per-body adj
// slot-rotation wait. 4 waves/WG share the j-chunk panel. Body: 4 ds_read
// B-frags + 2 ds_read w2 (lgkmcnt); adj = only vmcnt user, depth-2 ping-pong
// per subtile. 16 blocks of 32 cols, unrolled x2.
#define AF_ONE(AF, AD0, AD1, W20, W21, WH1, RS)                          \
    _Pragma("unroll")                                                    \
    for (int e = 0; e < 4; ++e) {                                        \
      float t0 = (WH1) + (W20)[e];                                       \
      t0 = fmaxf(t0, 0.2f * t0);            /* leaky_relu, scale-inv */  \
      float p0 = exp2f(t0) * (AD0)[e];      /* mask: adj is 0.0/1.0 */   \
      unsigned int pu0 = __float_as_uint(p0) & 0xFFFF0000u;              \
      RS += __uint_as_float(pu0);           /* denom matches bf16 num */ \
      AF[e] = (short)(pu0 >> 16);                                        \
      float t1 = (WH1) + (W21)[e];                                       \
      t1 = fmaxf(t1, 0.2f * t1);                                         \
      float p1 = exp2f(t1) * (AD1)[e];                                   \
      unsigned int pu1 = __float_as_uint(p1) & 0xFFFF0000u;              \
      RS += __uint_as_float(pu1);                                        \
      AF[4 + e] = (short)(pu1 >> 16);                                    \
    }

#define GAT_BODY(A00,A01, A10,A11, A20,A21, A30,A31, BLK, JPF)           \
  {                                                                      \
    const unsigned short* pb = panel + (BLK) * 2048 + lane * 8;          \
    short8 b0 = *(const short8*)(pb);                                    \
    short8 b1 = *(const short8*)(pb + 512);                              \
    short8 b2 = *(const short8*)(pb + 1024);                             \
    short8 b3 = *(const short8*)(pb + 1536);                             \
    const float* wp = w2lds + (BLK) * 32 + q * 8;                        \
    f32x4 w20 = *(const f32x4*)(wp);                                     \
    f32x4 w21 = *(const f32x4*)(wp + 4);                                 \
    short8 af0, af1, af2, af3;                                           \
    AF_ONE(af0, A00, A01, w20, w21, wh1_0, rsum0);                       \
    AF_ONE(af1, A10, A11, w20, w21, wh1_1, rsum1);                       \
    AF_ONE(af2, A20, A21, w20, w21, wh1_2, rsum2);                       \
    AF_ONE(af3, A30, A31, w20, w21, wh1_3, rsum3);                       \
    A00 = NTL(adjrow0 + (JPF)); A01 = NTL(adjrow0 + (JPF) + 4);          \
    A10 = NTL(adjrow1 + (JPF)); A11 = NTL(adjrow1 + (JPF) + 4);          \
    A20 = NTL(adjrow2 + (JPF)); A21 = NTL(adjrow2 + (JPF) + 4);          \
    A30 = NTL(adjrow3 + (JPF)); A31 = NTL(adjrow3 + (JPF) + 4);          \
    c00 = __builtin_amdgcn_mfma_f32_16x16x32_bf16(af0, b0, c00, 0,0,0);  \
    c01 = __builtin_amdgcn_mfma_f32_16x16x32_bf16(af0, b1, c01, 0,0,0);  \
    c02 = __builtin_amdgcn_mfma_f32_16x16x32_bf16(af0, b2, c02, 0,0,0);  \
    c03 = __builtin_amdgcn_mfma_f32_16x16x32_bf16(af0, b3, c03, 0,0,0);  \
    c10 = __builtin_amdgcn_mfma_f32_16x16x32_bf16(af1, b0, c10, 0,0,0);  \
    c11 = __builtin_amdgcn_mfma_f32_16x16x32_bf16(af1, b1, c11, 0,0,0);  \
    c12 = __builtin_amdgcn_mfma_f32_16x16x32_bf16(af1, b2, c12, 0,0,0);  \
    c13 = __builtin_amdgcn_mfma_f32_16x16x32_bf16(af1, b3, c13, 0,0,0);  \
    c20 = __builtin_amdgcn_mfma_f32_16x16x32_bf16(af2, b0, c20, 0,0,0);  \
    c21 = __builtin_amdgcn_mfma_f32_16x16x32_bf16(af2, b1, c21, 0,0,0);  \
    c22 = __builtin_amdgcn_mfma_f32_16x16x32_bf16(af2, b2, c22, 0,0,0);  \
    c23 = __builtin_amdgcn_mfma_f32_16x16x32_bf16(af2, b3, c23, 0,0,0);  \
    c30 = __builtin_amdgcn_mfma_f32_16x16x32_bf16(af3, b0, c30, 0,0,0);  \
    c31 = __builtin_amdgcn_mfma_f32_16x16x32_bf16(af3, b1, c31, 0,0,0);  \
    c32 = __builtin_amdgcn_mfma_f32_16x16x32_bf16(af3, b2, c32, 0,0,0);  \
    c33 = __builtin_amdgcn_mfma_f32_16x16x32_bf16(af3, b3, c33, 0,0,0);  \
  }

__global__ __launch_bounds__(256, 2) void gat_phaseB(
    const float* __restrict__ adj, const unsigned short* __restrict__ WhP,
    const float* __restrict__ Wh1, const float* __restrict__ Wh2,
    float* __restrict__ accbuf, float* __restrict__ denbuf, int nslices)
{
  const int wid  = threadIdx.x >> 6;
  const int lane = threadIdx.x & 63;
  // 4 waves of a WG share the j-chunk, cover 4 row-groups of 64
  const int jc   = blockIdx.x % SJ;
  const int rg   = (blockIdx.x / SJ) * 4 + wid;   // 64-row group, 0..127
  const int m = lane & 15;
  const int q = lane >> 4;
  const int r0 = rg * 64 + m;
  const int r1 = r0 + 16, r2 = r0 + 32, r3 = r0 + 48;
  const float wh1_0 = Wh1[r0], wh1_1 = Wh1[r1];
  const float wh1_2 = Wh1[r2], wh1_3 = Wh1[r3];
  // per-lane bases with the q*8 element offset folded in
  const float* adjrow0 = adj + (size_t)r0 * NN + q * 8;
  const float* adjrow1 = adj + (size_t)r1 * NN + q * 8;
  const float* adjrow2 = adj + (size_t)r2 * NN + q * 8;
  const float* adjrow3 = adj + (size_t)r3 * NN + q * 8;

  const int jbeg = jc * JCHUNK;

  // depth-2 ping-pong adj slots x 4 subtiles
  f32x4 aA00,aA01, aA10,aA11, aA20,aA21, aA30,aA31;   // even blocks
  f32x4 aB00,aB01, aB10,aB11, aB20,aB21, aB30,aB31;   // odd blocks
  aA00 = NTL(adjrow0 + jbeg);      aA01 = NTL(adjrow0 + jbeg + 4);
  aA10 = NTL(adjrow1 + jbeg);      aA11 = NTL(adjrow1 + jbeg + 4);
  aA20 = NTL(adjrow2 + jbeg);      aA21 = NTL(adjrow2 + jbeg + 4);
  aA30 = NTL(adjrow3 + jbeg);      aA31 = NTL(adjrow3 + jbeg + 4);
  aB00 = NTL(adjrow0 + jbeg + 32); aB01 = NTL(adjrow0 + jbeg + 36);
  aB10 = NTL(adjrow1 + jbeg + 32); aB11 = NTL(adjrow1 + jbeg + 36);
  aB20 = NTL(adjrow2 + jbeg + 32); aB21 = NTL(adjrow2 + jbeg + 36);
  aB30 = NTL(adjrow3 + jbeg + 32); aB31 = NTL(adjrow3 + jbeg + 36);

  // ---- LDS: 64 KB packed-B panel + 2 KB Wh2 chunk for this jc
  __shared__ __align__(16) unsigned short panel[16 * 2048];
  __shared__ __align__(16) float w2lds[JCHUNK];
  {
    const f32x4* src = (const f32x4*)(WhP + (size_t)jc * 16 * 2048) + threadIdx.x;
    f32x4* dst = (f32x4*)panel + threadIdx.x;
#pragma unroll
    for (int k = 0; k < 16; ++k)
      dst[k * 256] = src[k * 256];     // 256 thr x 16B = 4 KB per step
    if (threadIdx.x < JCHUNK / 4)
      ((f32x4*)w2lds)[threadIdx.x] =
          ((const f32x4*)(Wh2 + jbeg))[threadIdx.x];
  }
  __syncthreads();

  f32x4 c00 = {0.f,0.f,0.f,0.f}, c01 = c00, c02 = c00, c03 = c00;
  f32x4 c10 = c00, c11 = c00, c12 = c00, c13 = c00;
  f32x4 c20 = c00, c21 = c00, c22 = c00, c23 = c00;
  f32x4 c30 = c00, c31 = c00, c32 = c00, c33 = c00;
  float rsum0 = 0.f, rsum1 = 0.f, rsum2 = 0.f, rsum3 = 0.f;

  // 16 blocks of 32 columns; unrolled x2 -> 8 static double-bodies. Tail
  // prefetches wrap (valid addresses, values unused).
#pragma unroll
  for (int bb = 0; bb < 16; bb += 2) {
    GAT_BODY(aA00,aA01, aA10,aA11, aA20,aA21, aA30,aA31,
             bb,     jbeg + ((bb + 2) & 15) * 32);
    GAT_BODY(aB00,aB01, aB10,aB11, aB20,aB21, aB30,aB31,
             bb + 1, jbeg + ((bb + 3) & 15) * 32);
  }

  // row-sums: combine the 4 k-quads; every lane ends with full sum for its m
  rsum0 += __shfl_xor(rsum0, 16); rsum0 += __shfl_xor(rsum0, 32);
  rsum1 += __shfl_xor(rsum1, 16); rsum1 += __shfl_xor(rsum1, 32);
  rsum2 += __shfl_xor(rsum2, 16); rsum2 += __shfl_xor(rsum2, 32);
  rsum3 += __shfl_xor(rsum3, 16); rsum3 += __shfl_xor(rsum3, 32);

  const int slice = (nslices > 1) ? jc : 0;
  float* accout = accbuf + (size_t)slice * (NN * FOUT);
  float* denout = denbuf + slice * NN;
  f32x4 cc[4][4] = {{c00, c01, c02, c03}, {c10, c11, c12, c13},
                    {c20, c21, c22, c23}, {c30, c31, c32, c33}};
  float rs[4] = {rsum0, rsum1, rsum2, rsum3};
  if (nslices > 1) {            // roomy ws: plain per-slice stores
    if (q == 0) {
#pragma unroll
      for (int s = 0; s < 4; ++s) denout[r0 + s * 16] = rs[s];
    }
#pragma unroll
    for (int s = 0; s < 4; ++s)
#pragma unroll
      for (int ft = 0; ft < 4; ++ft)
#pragma unroll
        for (int r = 0; r < 4; ++r)
          accout[(rg * 64 + s * 16 + q * 4 + r) * FOUT + ft * 16 + m] = cc[s][ft][r];
  } else {                      // tight ws: atomic accumulate (zeroed first)
    if (q == 0) {
#pragma unroll
      for (int s = 0; s < 4; ++s) atomicAdd(&denout[r0 + s * 16], rs[s]);
    }
#pragma unroll
    for (int s = 0; s < 4; ++s)
#pragma unroll
      for (int ft = 0; ft < 4; ++ft)
#pragma unroll
        for (int r = 0; r < 4; ++r)
          atomicAdd(&accout[(rg * 64 + s * 16 + q * 4 + r) * FOUT + ft * 16 + m],
                    cc[s][ft][r]);
  }
}

// ---------------------------------------------------------------- Phase C ---
// elu(acc/den), vectorized f32x4 per thread.
__global__ __launch_bounds__(256) void gat_phaseC(
    const float* __restrict__ accbuf, const float* __restrict__ denbuf,
    float* __restrict__ out, int nslices)
{
  const int idx4 = blockIdx.x * 256 + threadIdx.x;   // f32x4 index
  const int idx  = idx4 * 4;
  const int row  = idx >> 6;    // FOUT = 64; 4 elems stay within one row
  f32x4 s = {0.f, 0.f, 0.f, 0.f};
  float d = 0.f;
  for (int sl = 0; sl < nslices; ++sl) {
    f32x4 v = *(const f32x4*)(accbuf + (size_t)sl * (NN * FOUT) + idx);
    s += v;
    d += denbuf[sl * NN + row];
  }
  float inv = 1.0f / d;
  f32x4 o;
#pragma unroll
  for (int e = 0; e < 4; ++e) {
    float v = s[e] * inv;
    o[e] = (v > 0.f) ? v : expm1f(v);   // elu, alpha=1
  }
  *(f32x4*)(out + idx) = o;
}

// ------------------------------------------------------------------ launch --
extern "C" void kernel_launch(void* const* d_in, const int* in_sizes, int n_in,
                              void* d_out, int out_size, void* d_ws, size_t ws_size,
                              hipStream_t stream)
{
  const float* x   = (const float*)d_in[0];   // [8192,128]
  const float* adj = (const float*)d_in[1];   // [8192,8192]
  const float* W   = (const float*)d_in[2];   // [128,64]
  const float* a   = (const float*)d_in[3];   // [128,1]
  float* out = (float*)d_out;                 // [8192,64] fp32

  const size_t accEl = (size_t)NN * FOUT;
  const size_t whpBytes = (size_t)(NN / 32) * 4 * 512 * 2;   // 1 MB packed B
  const size_t roomyBytes = (size_t)SJ * accEl * 4 + (size_t)SJ * NN * 4
                          + (size_t)NN * 8 + whpBytes;
  const int nslices = (ws_size >= roomyBytes) ? SJ : 1;

  char* ws = (char*)d_ws;
  float* accbuf = (float*)ws;
  size_t off = (size_t)nslices * accEl * 4;
  float* denbuf = (float*)(ws + off); off += (size_t)nslices * NN * 4;
  float* Wh1 = (float*)(ws + off);    off += (size_t)NN * 4;
  float* Wh2 = (float*)(ws + off);    off += (size_t)NN * 4;
  unsigned short* WhP = (unsigned short*)(ws + off);

  if (nslices == 1)   // atomic path needs zeroed acc+den (contiguous)
    hipMemsetAsync(accbuf, 0, accEl * 4 + (size_t)NN * 4, stream);

  gat_phaseA<<<NN / 16, 256, 0, stream>>>(x, W, a, WhP, Wh1, Wh2);
  gat_phaseB<<<((NN / 64) * SJ) / 4, 256, 0, stream>>>(adj, WhP, Wh1, Wh2,
                                                       accbuf, denbuf, nslices);
  gat_phaseC<<<(NN * FOUT) / 4 / 256, 256, 0, stream>>>(accbuf, denbuf, out, nslices);
}